// Round 1
// baseline (40.333 us; speedup 1.0000x reference)
//
#include <hip/hip_runtime.h>

// out[i] = idx[3i]*8192 + idx[3i+1]*16 + idx[3i+2]   (int32)
// Strides are fixed by VAR_SHAPE=(512,512,16) -> [8192,16,1].

#define STRIDE0 8192
#define STRIDE1 16

// Each thread: 4 tuples = 12 ints = 3x int4 loads (16B-aligned, stride 48B)
// + 1x int4 store. Fully vectorized, zero wasted bytes.
__global__ __launch_bounds__(256) void linidx_quad_kernel(
    const int* __restrict__ idx, int* __restrict__ out, int nquads) {
    int t = blockIdx.x * blockDim.x + threadIdx.x;
    if (t >= nquads) return;

    const int4* p = reinterpret_cast<const int4*>(idx) + (size_t)t * 3;
    int4 a = p[0];
    int4 b = p[1];
    int4 c = p[2];

    int4 o;
    o.x = a.x * STRIDE0 + a.y * STRIDE1 + a.z;
    o.y = a.w * STRIDE0 + b.x * STRIDE1 + b.y;
    o.z = b.z * STRIDE0 + b.w * STRIDE1 + c.x;
    o.w = c.y * STRIDE0 + c.z * STRIDE1 + c.w;

    reinterpret_cast<int4*>(out)[t] = o;
}

// Scalar tail for N % 4 != 0 (not hit at N=16M, kept for generality).
__global__ void linidx_tail_kernel(const int* __restrict__ idx,
                                   int* __restrict__ out,
                                   int start, int n) {
    int i = start + blockIdx.x * blockDim.x + threadIdx.x;
    if (i >= n) return;
    out[i] = idx[3 * i] * STRIDE0 + idx[3 * i + 1] * STRIDE1 + idx[3 * i + 2];
}

extern "C" void kernel_launch(void* const* d_in, const int* in_sizes, int n_in,
                              void* d_out, int out_size, void* d_ws, size_t ws_size,
                              hipStream_t stream) {
    const int* idx = (const int*)d_in[0];
    int* out = (int*)d_out;

    int n = out_size;        // N tuples
    int nquads = n / 4;
    int tail = n - nquads * 4;

    if (nquads > 0) {
        dim3 block(256);
        dim3 grid((nquads + 255) / 256);
        linidx_quad_kernel<<<grid, block, 0, stream>>>(idx, out, nquads);
    }
    if (tail > 0) {
        linidx_tail_kernel<<<1, 64, 0, stream>>>(idx, out, nquads * 4, n);
    }
}